// Round 4
// baseline (1004.622 us; speedup 1.0000x reference)
//
#include <hip/hip_runtime.h>
#include <hip/hip_bf16.h>
#include <cstdint>
#include <cstddef>

typedef __bf16 bf16;
typedef __bf16 bf16x4 __attribute__((ext_vector_type(4)));
typedef __bf16 bf16x8 __attribute__((ext_vector_type(8)));
typedef float f32x4 __attribute__((ext_vector_type(4)));

__device__ __forceinline__ f32x4 mfma16(bf16x8 a, bf16x8 b, f32x4 c) {
    return __builtin_amdgcn_mfma_f32_16x16x32_bf16(a, b, c, 0, 0, 0);
}

__device__ __forceinline__ void gload_lds16(const void* g, void* l) {
    __builtin_amdgcn_global_load_lds((const __attribute__((address_space(1))) void*)g,
                                     (__attribute__((address_space(3))) void*)l, 16, 0, 0);
}

__device__ __forceinline__ bf16x8 load8_or_zero(const bf16* p, bool live) {
    bf16x8 z = {};
    return live ? *(const bf16x8*)p : z;
}

// ---------------- weight transpose + fp32->bf16 cast: W[K][N] -> WT[N][K] ----------------
__global__ __launch_bounds__(256) void transpose_w(const float* __restrict__ W,
                                                   bf16* __restrict__ WT, int K, int N) {
    __shared__ float tile[32][33];
    int n0 = blockIdx.x * 32, k0 = blockIdx.y * 32;
    int cc = threadIdx.x & 31, rr0 = threadIdx.x >> 5;
#pragma unroll
    for (int rr = 0; rr < 4; ++rr) {
        int r = rr0 + rr * 8;
        tile[r][cc] = W[(size_t)(k0 + r) * N + n0 + cc];
    }
    __syncthreads();
#pragma unroll
    for (int rr = 0; rr < 4; ++rr) {
        int r = rr0 + rr * 8;
        WT[(size_t)(n0 + r) * K + k0 + cc] = (bf16)tile[cc][r];
    }
}

// ---------------- zero pad rows 72..79 of vt (needed every call: ws is re-poisoned) -------
__global__ __launch_bounds__(256) void vt_zero(bf16* __restrict__ vt) {
    int t = blockIdx.x * 256 + threadIdx.x;        // 0..131071
    int bh = t >> 10, o = (t & 1023) * 8;
    bf16x8 z = {};
    *(bf16x8*)(vt + ((size_t)bh * 80 + 72) * 1024 + o) = z;
}

// ---------------- adaLN modulation: mod[8][6912] = silu(c) @ w_ada + b_ada ----------------
__global__ __launch_bounds__(256) void ada_kernel(const float* __restrict__ c,
                                                  const float* __restrict__ w,
                                                  const float* __restrict__ b,
                                                  float* __restrict__ mod) {
    __shared__ float sc[8 * 1152];
    int tid = threadIdx.x;
    for (int i = tid; i < 8 * 1152; i += 256) {
        float v = c[i];
        sc[i] = v / (1.f + __expf(-v));
    }
    __syncthreads();
    int j = blockIdx.x * 256 + tid;
    float acc[8] = {};
    for (int k = 0; k < 1152; ++k) {
        float wv = w[(size_t)k * 6912 + j];
#pragma unroll
        for (int bb = 0; bb < 8; ++bb) acc[bb] += sc[bb * 1152 + k] * wv;
    }
    float bj = b[j];
#pragma unroll
    for (int bb = 0; bb < 8; ++bb) mod[(size_t)bb * 6912 + j] = acc[bb] + bj;
}

// ---------------- LayerNorm (eps 1e-6, non-affine) + modulate -> bf16 ----------------
__global__ __launch_bounds__(256) void ln_mod(const float* __restrict__ X,
                                              const float* __restrict__ mod,
                                              bf16* __restrict__ out,
                                              int ch_sh, int ch_sc) {
    int t = blockIdx.x;
    int b = t >> 10;
    __shared__ float row[1152];
    __shared__ float rs_[4], rs2_[4];
    int tid = threadIdx.x;
    float s = 0.f, s2 = 0.f;
    for (int i = tid * 4; i < 1152; i += 1024) {
        float4 v = *(const float4*)(X + (size_t)t * 1152 + i);
        *(float4*)(row + i) = v;
        s += v.x + v.y + v.z + v.w;
        s2 += v.x * v.x + v.y * v.y + v.z * v.z + v.w * v.w;
    }
#pragma unroll
    for (int off = 32; off; off >>= 1) { s += __shfl_xor(s, off); s2 += __shfl_xor(s2, off); }
    if ((tid & 63) == 0) { rs_[tid >> 6] = s; rs2_[tid >> 6] = s2; }
    __syncthreads();
    float sum = rs_[0] + rs_[1] + rs_[2] + rs_[3];
    float sum2 = rs2_[0] + rs2_[1] + rs2_[2] + rs2_[3];
    float mu = sum * (1.f / 1152.f);
    float var = sum2 * (1.f / 1152.f) - mu * mu;
    float rsg = rsqrtf(var + 1e-6f);
    const float* sh = mod + (size_t)b * 6912 + ch_sh * 1152;
    const float* scp = mod + (size_t)b * 6912 + ch_sc * 1152;
    for (int i = tid; i < 1152; i += 256) {
        float y = (row[i] - mu) * rsg;
        y = y * (scp[i] + 1.f) + sh[i];
        out[(size_t)t * 1152 + i] = (bf16)y;
    }
}

// ---------------- bf16 GEMM, 128x128 tile, BK=64, XOR-swizzled LDS ----------------
// A[M][K] bf16 row-major, BT[N][K] bf16 row-major.
// EPI 0: qkv scatter (+bias): q,k -> [bh][tok][72]; v -> transposed vt[bh][80][1024]
// EPI 1: proj: x + g_msa*val -> f32     EPI 2: fc1: gelu -> bf16
// EPI 3: fc2: x1 + g_mlp*val -> f32
template <int Nmat, int Kmat, int EPI>
__global__ __launch_bounds__(256, 2) void gemm_bf16(const bf16* __restrict__ A,
                                                    const bf16* __restrict__ BT,
                                                    const float* __restrict__ bias,
                                                    const float* __restrict__ extra,
                                                    const float* __restrict__ mod,
                                                    void* __restrict__ outp,
                                                    void* __restrict__ p2,
                                                    void* __restrict__ p3,
                                                    int mrow0) {
    constexpr int BM = 128, BN = 128, BK = 64;
    __shared__ __align__(16) bf16 As[BM * BK];
    __shared__ __align__(16) bf16 Bs[BN * BK];
    const int tid = threadIdx.x;
    const int lane = tid & 63;
    const int wv = tid >> 6;
    const int wr = wv >> 1, wc = wv & 1;
    const int lg = lane >> 4, li = lane & 15;
    constexpr int ntn = Nmat / BN;
    const int tm = blockIdx.x / ntn, tn = blockIdx.x % ntn;
    const int m0 = tm * BM, n0 = tn * BN;

    f32x4 acc[4][4] = {};

    const int srow = tid >> 3;
    const int schunk = tid & 7;

    for (int k0 = 0; k0 < Kmat; k0 += BK) {
#pragma unroll
        for (int ro = 0; ro < 4; ++ro) {
            int row = ro * 32 + srow;
            int csrc = schunk ^ (row & 7);
            gload_lds16(A + (size_t)(m0 + row) * Kmat + k0 + csrc * 8,
                        (char*)As + (ro * 256 + tid) * 16);
            gload_lds16(BT + (size_t)(n0 + row) * Kmat + k0 + csrc * 8,
                        (char*)Bs + (ro * 256 + tid) * 16);
        }
        __syncthreads();
#pragma unroll
        for (int kk = 0; kk < 2; ++kk) {
            bf16x8 af[4], bfr[4];
#pragma unroll
            for (int i = 0; i < 4; ++i) {
                int rowA = wr * 64 + i * 16 + li;
                int ch = (kk * 4 + lg) ^ (rowA & 7);
                af[i] = *(const bf16x8*)((const char*)As + rowA * 128 + ch * 16);
                int rowB = wc * 64 + i * 16 + li;
                int chb = (kk * 4 + lg) ^ (rowB & 7);
                bfr[i] = *(const bf16x8*)((const char*)Bs + rowB * 128 + chb * 16);
            }
#pragma unroll
            for (int i = 0; i < 4; ++i)
#pragma unroll
                for (int j = 0; j < 4; ++j)
                    acc[i][j] = mfma16(af[i], bfr[j], acc[i][j]);
        }
        __syncthreads();
    }

    if constexpr (EPI == 0) {
        bf16* qb = (bf16*)outp;
        bf16* kb = (bf16*)p2;
        bf16* vtp = (bf16*)p3;
#pragma unroll
        for (int j = 0; j < 4; ++j) {
            int n = n0 + wc * 64 + j * 16 + li;
            float bn = bias[n];
            int sec = n / 1152;           // block-uniform (1152 = 9 tiles of 128)
            int nn = n - sec * 1152;
            int h = nn / 72, d = nn - h * 72;
            if (sec < 2) {
                bf16* dst = sec == 0 ? qb : kb;
#pragma unroll
                for (int i = 0; i < 4; ++i)
#pragma unroll
                    for (int r = 0; r < 4; ++r) {
                        int m = m0 + wr * 64 + i * 16 + lg * 4 + r;
                        int b = m >> 10, tok = m & 1023;
                        dst[((size_t)(b * 16 + h) * 1024 + tok) * 72 + d] =
                            (bf16)(acc[i][j][r] + bn);
                    }
            } else {
#pragma unroll
                for (int i = 0; i < 4; ++i) {
                    int m = m0 + wr * 64 + i * 16 + lg * 4;   // multiple of 4
                    int b = m >> 10, tok = m & 1023;
                    bf16x4 pk;
#pragma unroll
                    for (int r = 0; r < 4; ++r) pk[r] = (bf16)(acc[i][j][r] + bn);
                    *(bf16x4*)(vtp + ((size_t)(b * 16 + h) * 80 + d) * 1024 + tok) = pk;
                }
            }
        }
        return;
    }

#pragma unroll
    for (int i = 0; i < 4; ++i) {
#pragma unroll
        for (int j = 0; j < 4; ++j) {
            f32x4 v = acc[i][j];
            int n = n0 + wc * 64 + j * 16 + li;
            float bn = bias[n];
#pragma unroll
            for (int r = 0; r < 4; ++r) {
                int m = m0 + wr * 64 + i * 16 + lg * 4 + r;
                float val = v[r] + bn;
                size_t idx = (size_t)m * Nmat + n;
                if constexpr (EPI == 1) {
                    int b = (mrow0 + m) >> 10;
                    float g = mod[(size_t)b * 6912 + 2 * 1152 + n];
                    ((float*)outp)[idx] = extra[idx] + g * val;
                } else if constexpr (EPI == 2) {
                    float inner = 0.7978845608028654f * (val + 0.044715f * val * val * val);
                    float gl = 0.5f * val * (1.f + tanhf(inner));
                    ((bf16*)outp)[idx] = (bf16)gl;
                } else {
                    int b = (mrow0 + m) >> 10;
                    float g = mod[(size_t)b * 6912 + 5 * 1152 + n];
                    ((float*)outp)[idx] = extra[idx] + g * val;
                }
            }
        }
    }
}

// ---------------- qk-norm (eps 1e-5, affine), in place on [bh][tok][72] ----------------
__global__ __launch_bounds__(256) void qk_norm_ip(bf16* __restrict__ qb, bf16* __restrict__ kb,
                                                  const float* __restrict__ qw, const float* __restrict__ qbb,
                                                  const float* __restrict__ kw, const float* __restrict__ kbb) {
    int w = blockIdx.x * 4 + (threadIdx.x >> 6);   // 0..262143
    int lane = threadIdx.x & 63;
    int isk = w >> 17;
    int r = w & 131071;
    bf16* row = (isk ? kb : qb) + (size_t)r * 72;
    const float* ww = isk ? kw : qw;
    const float* wb = isk ? kbb : qbb;
    float v0 = (float)row[lane];
    float v1 = (lane < 8) ? (float)row[64 + lane] : 0.f;
    float s = v0 + v1, s2 = v0 * v0 + v1 * v1;
#pragma unroll
    for (int off = 32; off; off >>= 1) { s += __shfl_xor(s, off); s2 += __shfl_xor(s2, off); }
    float mu = s * (1.f / 72.f);
    float var = s2 * (1.f / 72.f) - mu * mu;
    float rsg = rsqrtf(var + 1e-5f);
    row[lane] = (bf16)((v0 - mu) * rsg * ww[lane] + wb[lane]);
    if (lane < 8) row[64 + lane] = (bf16)((v1 - mu) * rsg * ww[64 + lane] + wb[64 + lane]);
}

// ---------------- flash attention: per-wave 16 q rows, KV tiles of 32 ----------------
__global__ __launch_bounds__(256) void attn_kernel(const bf16* __restrict__ qb,
                                                   const bf16* __restrict__ kb,
                                                   const bf16* __restrict__ vt,
                                                   bf16* __restrict__ oat) {
    __shared__ __align__(16) bf16 plds[4][16][40];
    int bh = blockIdx.x >> 4, qt = blockIdx.x & 15;
    int wv = threadIdx.x >> 6, lane = threadIdx.x & 63;
    int q0 = qt * 64 + wv * 16;
    int lg = lane >> 4, li = lane & 15;
    const bf16* qrow = qb + (size_t)(bh * 1024 + q0) * 72;
    bf16x8 qf[3];
#pragma unroll
    for (int c2 = 0; c2 < 3; ++c2) {
        bool live = (c2 < 2) || (lg == 0);
        qf[c2] = load8_or_zero(qrow + (size_t)li * 72 + c2 * 32 + lg * 8, live);
    }

    f32x4 o[5] = {};
    float mrun[4], lrun[4] = {};
#pragma unroll
    for (int r = 0; r < 4; ++r) mrun[r] = -1e30f;
    const float scale = 0.11785113019775793f;  // 72^-0.5

    for (int kv0 = 0; kv0 < 1024; kv0 += 32) {
        f32x4 s0 = {}, s1 = {};
        const bf16* krow = kb + (size_t)(bh * 1024 + kv0) * 72;
#pragma unroll
        for (int c2 = 0; c2 < 3; ++c2) {
            bool live = (c2 < 2) || (lg == 0);
            bf16x8 kf0 = load8_or_zero(krow + (size_t)li * 72 + c2 * 32 + lg * 8, live);
            bf16x8 kf1 = load8_or_zero(krow + (size_t)(16 + li) * 72 + c2 * 32 + lg * 8, live);
            s0 = mfma16(qf[c2], kf0, s0);
            s1 = mfma16(qf[c2], kf1, s1);
        }
        float al[4];
#pragma unroll
        for (int r = 0; r < 4; ++r) {
            float a = s0[r] * scale, bb = s1[r] * scale;
            float mx = fmaxf(a, bb);
            mx = fmaxf(mx, __shfl_xor(mx, 1));
            mx = fmaxf(mx, __shfl_xor(mx, 2));
            mx = fmaxf(mx, __shfl_xor(mx, 4));
            mx = fmaxf(mx, __shfl_xor(mx, 8));
            float mn = fmaxf(mrun[r], mx);
            al[r] = __expf(mrun[r] - mn);
            mrun[r] = mn;
            float p0 = __expf(a - mn), p1 = __expf(bb - mn);
            float rs = p0 + p1;
            rs += __shfl_xor(rs, 1); rs += __shfl_xor(rs, 2);
            rs += __shfl_xor(rs, 4); rs += __shfl_xor(rs, 8);
            lrun[r] = lrun[r] * al[r] + rs;
            plds[wv][lg * 4 + r][li] = (bf16)p0;
            plds[wv][lg * 4 + r][16 + li] = (bf16)p1;
        }
#pragma unroll
        for (int dc = 0; dc < 5; ++dc)
#pragma unroll
            for (int r = 0; r < 4; ++r) o[dc][r] *= al[r];
        bf16x8 pa = *(const bf16x8*)(&plds[wv][li][lg * 8]);
        const bf16* vb = vt + ((size_t)bh * 80) * 1024 + kv0;
#pragma unroll
        for (int dc = 0; dc < 5; ++dc) {
            bf16x8 vf = *(const bf16x8*)(vb + (size_t)(dc * 16 + li) * 1024 + lg * 8);
            o[dc] = mfma16(pa, vf, o[dc]);
        }
    }
    int b = bh >> 4, h = bh & 15;
#pragma unroll
    for (int r = 0; r < 4; ++r) {
        float inv = 1.f / lrun[r];
        size_t orow = ((size_t)(b * 1024 + q0 + lg * 4 + r)) * 1152 + h * 72;
#pragma unroll
        for (int dc = 0; dc < 5; ++dc) {
            int d = dc * 16 + li;
            if (d < 72) oat[orow + d] = (bf16)(o[dc][r] * inv);
        }
    }
}

// ---------------- launch ----------------
extern "C" void kernel_launch(void* const* d_in, const int* in_sizes, int n_in,
                              void* d_out, int out_size, void* d_ws, size_t ws_size,
                              hipStream_t stream) {
    const float* x      = (const float*)d_in[0];
    const float* c      = (const float*)d_in[1];
    const float* w_ada  = (const float*)d_in[2];
    const float* b_ada  = (const float*)d_in[3];
    const float* w_qkv  = (const float*)d_in[4];
    const float* b_qkv  = (const float*)d_in[5];
    const float* qn_w   = (const float*)d_in[6];
    const float* qn_b   = (const float*)d_in[7];
    const float* kn_w   = (const float*)d_in[8];
    const float* kn_b   = (const float*)d_in[9];
    const float* w_proj = (const float*)d_in[10];
    const float* b_proj = (const float*)d_in[11];
    const float* w_fc1  = (const float*)d_in[12];
    const float* b_fc1  = (const float*)d_in[13];
    const float* w_fc2  = (const float*)d_in[14];
    const float* b_fc2  = (const float*)d_in[15];

    // ---- workspace layout: 109,666,304 B total ----
    // x1 lives in d_out (f32): proj writes it, ln_mod reads it, fc2 epilogue
    // does per-element read(extra)-then-write(outp) on the same address — safe.
    char* ws = (char*)d_ws;
    bf16* wqkvT  = (bf16*)(ws + 0);             //  7,962,624
    bf16* wprojT = (bf16*)(ws + 7962624);       //  2,654,208
    bf16* wfc1T  = (bf16*)(ws + 10616832);      // 10,616,832
    bf16* wfc2T  = (bf16*)(ws + 21233664);      // 10,616,832
    float* modb  = (float*)(ws + 31850496);     //    221,184
    bf16* actA   = (bf16*)(ws + 32071680);      // 18,874,368
    char* R      = ws + 50946048;               // 58,720,256 region
    bf16* qbuf = (bf16*)R;                      // 18,874,368 (attn phase)
    bf16* kbuf = (bf16*)(R + 18874368);         // 18,874,368 (attn phase)
    bf16* vtb  = (bf16*)(R + 37748736);         // 20,971,520 (attn phase)
    bf16* hbuf = (bf16*)R;                      // 37,748,736 (MLP phase, Mc=4096)
    float* x1  = (float*)d_out;                 // 37,748,736 (aliases output)

    const int nchunk = 2;
    const int Mc = 8192 / nchunk;

    transpose_w<<<dim3(3456 / 32, 1152 / 32), 256, 0, stream>>>(w_qkv, wqkvT, 1152, 3456);
    transpose_w<<<dim3(1152 / 32, 1152 / 32), 256, 0, stream>>>(w_proj, wprojT, 1152, 1152);
    transpose_w<<<dim3(4608 / 32, 1152 / 32), 256, 0, stream>>>(w_fc1, wfc1T, 1152, 4608);
    transpose_w<<<dim3(1152 / 32, 4608 / 32), 256, 0, stream>>>(w_fc2, wfc2T, 4608, 1152);
    vt_zero<<<512, 256, 0, stream>>>(vtb);

    ada_kernel<<<27, 256, 0, stream>>>(c, w_ada, b_ada, modb);
    ln_mod<<<8192, 256, 0, stream>>>(x, modb, actA, 0, 1);
    gemm_bf16<3456, 1152, 0><<<64 * 27, 256, 0, stream>>>(actA, wqkvT, b_qkv, nullptr, nullptr,
                                                          qbuf, kbuf, vtb, 0);
    qk_norm_ip<<<65536, 256, 0, stream>>>(qbuf, kbuf, qn_w, qn_b, kn_w, kn_b);
    attn_kernel<<<2048, 256, 0, stream>>>(qbuf, kbuf, vtb, actA);
    gemm_bf16<1152, 1152, 1><<<64 * 9, 256, 0, stream>>>(actA, wprojT, b_proj, x, modb,
                                                         x1, nullptr, nullptr, 0);
    ln_mod<<<8192, 256, 0, stream>>>(x1, modb, actA, 3, 4);
    for (int cc = 0; cc < nchunk; ++cc) {
        size_t offA = (size_t)cc * Mc * 1152;
        gemm_bf16<4608, 1152, 2><<<(Mc / 128) * 36, 256, 0, stream>>>(
            actA + offA, wfc1T, b_fc1, nullptr, nullptr, hbuf, nullptr, nullptr, 0);
        gemm_bf16<1152, 4608, 3><<<(Mc / 128) * 9, 256, 0, stream>>>(
            hbuf, wfc2T, b_fc2, x1 + offA, modb, (float*)d_out + offA, nullptr, nullptr, cc * Mc);
    }
}